// Round 9
// baseline (484.321 us; speedup 1.0000x reference)
//
#include <hip/hip_runtime.h>

#define NN 50000
#define NE 625000
#define HD 128
#define CAP 40     // Poisson(12.5): P(deg>40) ~ 5e-11 -> zero expected drops
#define ZROW NN    // dedicated all-zero row in h tables for masked gather slots
#define DPB 768    // dsts per bucket block; LDS = 768*40*2 + 768*4 = 64512 B <= 64 KB
#define NBKT 66    // ceil(NN/DPB) blocks per relation

typedef __attribute__((ext_vector_type(8))) short short8;
typedef __attribute__((ext_vector_type(4))) float f32x4;
typedef __attribute__((ext_vector_type(4))) unsigned uint4v;

__device__ __forceinline__ unsigned short f2bf(float f) {
    unsigned u = __builtin_bit_cast(unsigned, f);
    u += 0x7FFFu + ((u >> 16) & 1u);
    return (unsigned short)(u >> 16);
}
__device__ __forceinline__ unsigned pack2(float lo, float hi) {
    return (unsigned)f2bf(lo) | ((unsigned)f2bf(hi) << 16);
}
__device__ __forceinline__ float bflo(unsigned v) { unsigned u = v << 16; return __builtin_bit_cast(float, u); }
__device__ __forceinline__ float bfhi(unsigned v) { unsigned u = v & 0xFFFF0000u; return __builtin_bit_cast(float, u); }

__device__ __forceinline__ void extract8(uint4v u, int j0, int cnt, unsigned* out) {
    unsigned raw[8];
    raw[0] = u.x & 0xFFFFu; raw[1] = u.x >> 16;
    raw[2] = u.y & 0xFFFFu; raw[3] = u.y >> 16;
    raw[4] = u.z & 0xFFFFu; raw[5] = u.z >> 16;
    raw[6] = u.w & 0xFFFFu; raw[7] = u.w >> 16;
    #pragma unroll
    for (int j = 0; j < 8; ++j) out[j] = (j0 + j < cnt) ? raw[j] : ZROW;
}

// Fused prep. Block ranges (bucket FIRST so embed/Wt hide under the scan):
//  [0,132): LDS-bucket build — block owns 768 dsts of one relation (rel=bid&1 ->
//           disjoint XCD parity under round-robin), scans the full edge list with
//           uint4 loads (L2-resident: 63 blocks share the same 2.5 MB streams),
//           LDS atomics for matches, fully-coalesced deg+bucket writeout.
//           No global atomics, no write-allocate churn, no deg memsets.
//  [132,12632): embed h0.  12632: zero rows.  [12633,13017): Wt/bcat.
__global__ __launch_bounds__(256) void k_prep(
    const float* __restrict__ x, const float* __restrict__ w,
    const float* __restrict__ b, unsigned* __restrict__ h0, unsigned* __restrict__ h1,
    const int* __restrict__ ei_f, const int* __restrict__ ei_s,
    int* __restrict__ degF, int* __restrict__ degS,
    unsigned short* __restrict__ bktF, unsigned short* __restrict__ bktS,
    const float* __restrict__ wrf0, const float* __restrict__ wtf0, const float* __restrict__ bf0,
    const float* __restrict__ wrs0, const float* __restrict__ wts0, const float* __restrict__ bs0,
    const float* __restrict__ wrf1, const float* __restrict__ wtf1, const float* __restrict__ bf1,
    const float* __restrict__ wrs1, const float* __restrict__ wts1, const float* __restrict__ bs1,
    unsigned short* __restrict__ Wt, float* __restrict__ bcat)
{
    __shared__ unsigned short lbkt[DPB * CAP];   // 61440 B
    __shared__ int ldeg[DPB];                    //  3072 B
    int bid = blockIdx.x, t = threadIdx.x;
    if (bid < 2 * NBKT) {
        int rel = bid & 1, idx = bid >> 1;       // idx 0..65
        const int* ei = rel ? ei_s : ei_f;
        int* deg = rel ? degS : degF;
        unsigned short* bkt = rel ? bktS : bktF;
        const unsigned lo = idx * DPB;
        const int nd = min(DPB, NN - (int)lo);
        for (int j = t; j < DPB; j += 256) ldeg[j] = 0;
        __syncthreads();
        const uint4v* dstv = (const uint4v*)(ei + NE);
        const uint4v* srcv = (const uint4v*)(ei);
        for (int i = t; i < NE / 4; i += 256) {
            uint4v d4 = dstv[i];
            uint4v s4 = srcv[i];
            unsigned dd;
            dd = d4.x - lo; if (dd < (unsigned)DPB) { int p = atomicAdd(&ldeg[dd], 1); if (p < CAP) lbkt[dd*CAP + p] = (unsigned short)s4.x; }
            dd = d4.y - lo; if (dd < (unsigned)DPB) { int p = atomicAdd(&ldeg[dd], 1); if (p < CAP) lbkt[dd*CAP + p] = (unsigned short)s4.y; }
            dd = d4.z - lo; if (dd < (unsigned)DPB) { int p = atomicAdd(&ldeg[dd], 1); if (p < CAP) lbkt[dd*CAP + p] = (unsigned short)s4.z; }
            dd = d4.w - lo; if (dd < (unsigned)DPB) { int p = atomicAdd(&ldeg[dd], 1); if (p < CAP) lbkt[dd*CAP + p] = (unsigned short)s4.w; }
        }
        __syncthreads();
        for (int j = t; j < nd; j += 256) deg[lo + j] = ldeg[j];
        const int ndw = nd * (CAP / 2);          // dwords of bucket payload
        unsigned* gb = (unsigned*)(bkt + (long)lo * CAP);
        const unsigned* lb = (const unsigned*)lbkt;
        for (int j = t; j < ndw; j += 256) gb[j] = lb[j];
    } else if (bid < 12632) {
        int i = (bid - 132) * 256 + t;           // [0, NN*64)
        int n = i >> 6, c = (i & 63) * 2;
        float x0 = x[n*3+0], x1 = x[n*3+1], x2 = x[n*3+2];
        float v0 = fmaf(x0, w[c],   fmaf(x1, w[HD+c],   fmaf(x2, w[2*HD+c],   b[c])));
        float v1 = fmaf(x0, w[c+1], fmaf(x1, w[HD+c+1], fmaf(x2, w[2*HD+c+1], b[c+1])));
        v0 = fmaxf(v0, 0.f); v1 = fmaxf(v1, 0.f);
        h0[i] = pack2(v0, v1);
    } else if (bid == 12632) {
        if (t < 64)       h0[(long)ZROW*64 + t] = 0u;
        else if (t < 128) h1[(long)ZROW*64 + (t - 64)] = 0u;
    } else {
        int i = (bid - 12633) * 256 + t;         // [0, 2*128*384)
        int ln = i / 384, k = i - ln * 384;      // ln = l*128 + n
        int l = ln >> 7, n = ln & 127;
        const float* wrf = l ? wrf1 : wrf0;
        const float* wrs = l ? wrs1 : wrs0;
        const float* wtf = l ? wtf1 : wtf0;
        const float* wts = l ? wts1 : wts0;
        float v;
        if (k < 128)      v = wrf[k*HD + n];
        else if (k < 256) v = wrs[(k-128)*HD + n];
        else              v = wtf[(k-256)*HD + n] + wts[(k-256)*HD + n];
        Wt[(long)ln*384 + k] = f2bf(0.5f * v);
        if (i < 256) {
            int ll = i >> 7, cc = i & 127;
            const float* bfp = ll ? bf1 : bf0;
            const float* bsp = ll ? bs1 : bs0;
            bcat[i] = 0.5f * (bfp[cc] + bsp[cc]);
        }
    }
}

// agg[n] = mean over bucket[n] of h[src], BOTH relations per wave (node n):
// 32 coalesced row-gathers in flight up front. Invalid slots -> zero row.
__global__ __launch_bounds__(256) void k_spmm(
    const unsigned* __restrict__ h,
    const int* __restrict__ degF, const int* __restrict__ degS,
    const unsigned short* __restrict__ bktF, const unsigned short* __restrict__ bktS,
    unsigned* __restrict__ aggF, unsigned* __restrict__ aggS)
{
    int w = threadIdx.x >> 6, lane = threadIdx.x & 63;
    int n = blockIdx.x * 4 + w;
    int dF = degF[n], dS = degS[n];
    int cF = min(dF, CAP), cS = min(dS, CAP);
    const unsigned short* rowF = bktF + (long)n*CAP;
    const unsigned short* rowS = bktS + (long)n*CAP;
    uint4v uF0 = *(const uint4v*)(rowF);
    uint4v uF1 = *(const uint4v*)(rowF + 8);
    uint4v uS0 = *(const uint4v*)(rowS);
    uint4v uS1 = *(const uint4v*)(rowS + 8);
    unsigned iF[16], iS[16];
    extract8(uF0, 0, cF, iF); extract8(uF1, 8, cF, iF + 8);
    extract8(uS0, 0, cS, iS); extract8(uS1, 8, cS, iS + 8);
    unsigned vF[16], vS[16];
    #pragma unroll
    for (int j = 0; j < 16; ++j) vF[j] = h[iF[j]*64u + lane];
    #pragma unroll
    for (int j = 0; j < 16; ++j) vS[j] = h[iS[j]*64u + lane];
    float aF0 = 0.f, aF1 = 0.f, aS0 = 0.f, aS1 = 0.f;
    #pragma unroll
    for (int j = 0; j < 16; ++j) { aF0 += bflo(vF[j]); aF1 += bfhi(vF[j]); }
    #pragma unroll
    for (int j = 0; j < 16; ++j) { aS0 += bflo(vS[j]); aS1 += bfhi(vS[j]); }
    // tails (P(deg>16) ~ 0.13)
    for (int j = 16; j < cF; j += 8) {
        uint4v u = *(const uint4v*)(rowF + j);
        unsigned ii[8];
        extract8(u, j, cF, ii);
        unsigned vv[8];
        #pragma unroll
        for (int q = 0; q < 8; ++q) vv[q] = h[ii[q]*64u + lane];
        #pragma unroll
        for (int q = 0; q < 8; ++q) { aF0 += bflo(vv[q]); aF1 += bfhi(vv[q]); }
    }
    for (int j = 16; j < cS; j += 8) {
        uint4v u = *(const uint4v*)(rowS + j);
        unsigned ii[8];
        extract8(u, j, cS, ii);
        unsigned vv[8];
        #pragma unroll
        for (int q = 0; q < 8; ++q) vv[q] = h[ii[q]*64u + lane];
        #pragma unroll
        for (int q = 0; q < 8; ++q) { aS0 += bflo(vv[q]); aS1 += bfhi(vv[q]); }
    }
    float invF = 1.f / fmaxf((float)dF, 1.f);
    float invS = 1.f / fmaxf((float)dS, 1.f);
    aggF[n*64 + lane] = pack2(aF0*invF, aF1*invF);
    aggS[n*64 + lane] = pack2(aS0*invS, aS1*invS);
}

// out[M,128] = [A0|A1|A2](M,384, bf16) @ W(384,128, bf16 Wt[n][k]) + bias.
// Wt staged through LDS frag-major (conflict-free ds_read_b128, 4x B-amortize).
// mode 0: relu -> bf16 h1. mode 1: fused classifier epilogue -> out6.
__global__ __launch_bounds__(256) void k_gemm(
    const unsigned short* __restrict__ A0, const unsigned short* __restrict__ A1,
    const unsigned short* __restrict__ A2,
    const unsigned short* __restrict__ Wt, const float* __restrict__ bias,
    unsigned short* __restrict__ outH, int mode,
    const float* __restrict__ ow, const float* __restrict__ ob,
    float* __restrict__ out6)
{
    __shared__ unsigned short Bs[16 * 64 * 8];   // 16 KB
    const int t = threadIdx.x;
    const int wv = t >> 6, lane = t & 63;
    const int m16 = lane & 15, quad = lane >> 4;
    const int row0 = blockIdx.x * 128 + wv * 32;
    f32x4 acc[2][8];
    #pragma unroll
    for (int mt = 0; mt < 2; ++mt)
        #pragma unroll
        for (int nt = 0; nt < 8; ++nt) acc[mt][nt] = (f32x4){0.f,0.f,0.f,0.f};

    for (int ch = 0; ch < 6; ++ch) {
        const int k0 = ch * 64;
        const unsigned short* src; int kofs;
        if (ch < 2)      { src = A0; kofs = k0; }
        else if (ch < 4) { src = A1; kofs = k0 - 128; }
        else             { src = A2; kofs = k0 - 256; }
        __syncthreads();
        #pragma unroll
        for (int i = 0; i < 4; ++i) {
            int flat = i * 256 + t;
            int fb = flat >> 6, ln = flat & 63;
            int nt = fb >> 1, kc2 = fb & 1;
            int mm = ln & 15, qq = ln >> 4;
            short8 v = *(const short8*)(Wt + (long)(nt*16 + mm)*384 + k0 + kc2*32 + qq*8);
            *(short8*)(Bs + flat*8) = v;
        }
        short8 a[2][2];
        #pragma unroll
        for (int mt = 0; mt < 2; ++mt) {
            int r = row0 + mt*16 + m16;
            #pragma unroll
            for (int kc2 = 0; kc2 < 2; ++kc2) {
                if (r < NN) a[mt][kc2] = *(const short8*)(src + (long)r*HD + kofs + kc2*32 + quad*8);
                else        a[mt][kc2] = short8{0,0,0,0,0,0,0,0};
            }
        }
        __syncthreads();
        #pragma unroll
        for (int kc2 = 0; kc2 < 2; ++kc2)
            #pragma unroll
            for (int nt = 0; nt < 8; ++nt) {
                short8 bfr = *(const short8*)(Bs + ((nt*2 + kc2)*64 + lane)*8);
                acc[0][nt] = __builtin_amdgcn_mfma_f32_16x16x32_bf16(a[0][kc2], bfr, acc[0][nt], 0, 0, 0);
                acc[1][nt] = __builtin_amdgcn_mfma_f32_16x16x32_bf16(a[1][kc2], bfr, acc[1][nt], 0, 0, 0);
            }
    }

    float bs[8];
    #pragma unroll
    for (int nt = 0; nt < 8; ++nt) bs[nt] = bias[nt*16 + m16];

    if (mode == 0) {
        #pragma unroll
        for (int mt = 0; mt < 2; ++mt)
            #pragma unroll
            for (int reg = 0; reg < 4; ++reg) {
                int r = row0 + mt*16 + quad*4 + reg;
                if (r >= NN) continue;
                #pragma unroll
                for (int nt = 0; nt < 8; ++nt) {
                    float v = fmaxf(acc[mt][nt][reg] + bs[nt], 0.f);
                    outH[(long)r*HD + nt*16 + m16] = f2bf(v);
                }
            }
    } else {
        float owr[8][6];
        #pragma unroll
        for (int nt = 0; nt < 8; ++nt) {
            int c = nt*16 + m16;
            #pragma unroll
            for (int j = 0; j < 6; ++j) owr[nt][j] = ow[c*6 + j];
        }
        #pragma unroll
        for (int mt = 0; mt < 2; ++mt)
            #pragma unroll
            for (int reg = 0; reg < 4; ++reg) {
                int r = row0 + mt*16 + quad*4 + reg;
                float tj[6] = {0,0,0,0,0,0};
                #pragma unroll
                for (int nt = 0; nt < 8; ++nt) {
                    float hv = acc[mt][nt][reg] + bs[nt];
                    #pragma unroll
                    for (int j = 0; j < 6; ++j) tj[j] = fmaf(hv, owr[nt][j], tj[j]);
                }
                #pragma unroll
                for (int mask = 1; mask < 16; mask <<= 1)
                    #pragma unroll
                    for (int j = 0; j < 6; ++j) tj[j] += __shfl_xor(tj[j], mask, 64);
                if (m16 == 0 && r < NN) {
                    #pragma unroll
                    for (int j = 0; j < 6; ++j) out6[(long)r*6 + j] = tj[j] + ob[j];
                }
            }
    }
}

extern "C" void kernel_launch(void* const* d_in, const int* in_sizes, int n_in,
                              void* d_out, int out_size, void* d_ws, size_t ws_size,
                              hipStream_t stream)
{
    const float* x     = (const float*)d_in[0];
    const int*   ei_f  = (const int*)d_in[1];
    const int*   ei_s  = (const int*)d_in[2];
    const float* emb_w = (const float*)d_in[3];
    const float* emb_b = (const float*)d_in[4];
    const float* wr0f  = (const float*)d_in[5];
    const float* wt0f  = (const float*)d_in[6];
    const float* b0f   = (const float*)d_in[7];
    const float* wr0s  = (const float*)d_in[8];
    const float* wt0s  = (const float*)d_in[9];
    const float* b0s   = (const float*)d_in[10];
    const float* wr1f  = (const float*)d_in[11];
    const float* wt1f  = (const float*)d_in[12];
    const float* b1f   = (const float*)d_in[13];
    const float* wr1s  = (const float*)d_in[14];
    const float* wt1s  = (const float*)d_in[15];
    const float* b1s   = (const float*)d_in[16];
    const float* out_w = (const float*)d_in[17];
    const float* out_b = (const float*)d_in[18];
    float* out = (float*)d_out;

    char* ws = (char*)d_ws;
    size_t off = 0;
    auto alloc = [&](size_t bytes) { char* p = ws + off; off += (bytes + 255) & ~255ULL; return p; };
    unsigned* h0   = (unsigned*)alloc((size_t)(NN+1)*64*4);   // bf16x2 packed, +1 zero row
    unsigned* h1   = (unsigned*)alloc((size_t)(NN+1)*64*4);
    unsigned* aggF = (unsigned*)alloc((size_t)NN*64*4);
    unsigned* aggS = (unsigned*)alloc((size_t)NN*64*4);
    int*   degF = (int*)alloc((size_t)NN*4);
    int*   degS = (int*)alloc((size_t)NN*4);
    unsigned short* bktF = (unsigned short*)alloc((size_t)(NBKT*DPB)*CAP*2);
    unsigned short* bktS = (unsigned short*)alloc((size_t)(NBKT*DPB)*CAP*2);
    unsigned short* Wt = (unsigned short*)alloc((size_t)2*128*384*2);
    float* bcat = (float*)alloc((size_t)2*HD*4);

    k_prep<<<13017, 256, 0, stream>>>(x, emb_w, emb_b, h0, h1,
                                      ei_f, ei_s, degF, degS, bktF, bktS,
                                      wr0f, wt0f, b0f, wr0s, wt0s, b0s,
                                      wr1f, wt1f, b1f, wr1s, wt1s, b1s,
                                      Wt, bcat);
    k_spmm<<<NN/4, 256, 0, stream>>>(h0, degF, degS, bktF, bktS, aggF, aggS);
    k_gemm<<<(NN + 127)/128, 256, 0, stream>>>((const unsigned short*)aggF, (const unsigned short*)aggS,
                                               (const unsigned short*)h0, Wt, bcat,
                                               (unsigned short*)h1, 0, out_w, out_b, out);
    k_spmm<<<NN/4, 256, 0, stream>>>(h1, degF, degS, bktF, bktS, aggF, aggS);
    k_gemm<<<(NN + 127)/128, 256, 0, stream>>>((const unsigned short*)aggF, (const unsigned short*)aggS,
                                               (const unsigned short*)h1, Wt + 128*384, bcat + HD,
                                               (unsigned short*)h1, 1, out_w, out_b, out);
}

// Round 10
// 276.844 us; speedup vs baseline: 1.7494x; 1.7494x over previous
//
#include <hip/hip_runtime.h>

#define NN 50000
#define NE 625000
#define HD 128
#define CAP 40     // Poisson(12.5): P(deg>40) ~ 5e-11 -> zero expected drops
#define ZROW NN    // dedicated all-zero row in h tables for masked gather slots

typedef __attribute__((ext_vector_type(8))) short short8;
typedef __attribute__((ext_vector_type(4))) float f32x4;
typedef __attribute__((ext_vector_type(4))) unsigned uint4v;

__device__ __forceinline__ unsigned short f2bf(float f) {
    unsigned u = __builtin_bit_cast(unsigned, f);
    u += 0x7FFFu + ((u >> 16) & 1u);
    return (unsigned short)(u >> 16);
}
__device__ __forceinline__ unsigned pack2(float lo, float hi) {
    return (unsigned)f2bf(lo) | ((unsigned)f2bf(hi) << 16);
}
__device__ __forceinline__ float bflo(unsigned v) { unsigned u = v << 16; return __builtin_bit_cast(float, u); }
__device__ __forceinline__ float bfhi(unsigned v) { unsigned u = v & 0xFFFF0000u; return __builtin_bit_cast(float, u); }

__device__ __forceinline__ void extract8(uint4v u, int j0, int cnt, unsigned* out) {
    unsigned raw[8];
    raw[0] = u.x & 0xFFFFu; raw[1] = u.x >> 16;
    raw[2] = u.y & 0xFFFFu; raw[3] = u.y >> 16;
    raw[4] = u.z & 0xFFFFu; raw[5] = u.z >> 16;
    raw[6] = u.w & 0xFFFFu; raw[7] = u.w >> 16;
    #pragma unroll
    for (int j = 0; j < 8; ++j) out[j] = (j0 + j < cnt) ? raw[j] : ZROW;
}

// Fused prep, bucket blocks FIRST (blocks dispatch roughly in blockIdx order, so
// the latency-bound scatter — the 58 µs critical path — starts at t=0 and the
// streaming embed/Wt blocks back-fill idle issue slots under it):
//  [0,3920): XCD-binned bucket build (global atomics; round-9's LDS variant
//            forced 64.5 KB LDS on ALL blocks of the fused kernel -> 7% occupancy).
//  [3920,16420): embed h0.  16420: zero rows.  [16421,16805): Wt/bcat.
// deg arrays zeroed by hipMemsetAsync BEFORE this dispatch.
__global__ __launch_bounds__(256) void k_prep(
    const float* __restrict__ x, const float* __restrict__ w,
    const float* __restrict__ b, unsigned* __restrict__ h0, unsigned* __restrict__ h1,
    const int* __restrict__ ei_f, const int* __restrict__ ei_s,
    int* __restrict__ degF, int* __restrict__ degS,
    unsigned short* __restrict__ bktF, unsigned short* __restrict__ bktS,
    const float* __restrict__ wrf0, const float* __restrict__ wtf0, const float* __restrict__ bf0,
    const float* __restrict__ wrs0, const float* __restrict__ wts0, const float* __restrict__ bs0,
    const float* __restrict__ wrf1, const float* __restrict__ wtf1, const float* __restrict__ bf1,
    const float* __restrict__ wrs1, const float* __restrict__ wts1, const float* __restrict__ bs1,
    unsigned short* __restrict__ Wt, float* __restrict__ bcat)
{
    int bid = blockIdx.x, t = threadIdx.x;
    if (bid < 3920) {
        int rel = bid >= 1960;
        int bqq = bid - rel * 1960;
        int cls = bqq & 7;                       // -> fixed XCD under round-robin
        int chunk = bqq >> 3;                    // [0, 245)
        const int* ei; int* deg; unsigned short* bkt;
        if (rel == 0) { ei = ei_f; deg = degF; bkt = bktF; }
        else          { ei = ei_s; deg = degS; bkt = bktS; }
        const int lo = cls * 6250, hi = lo + 6250;
        int e0 = chunk * 2560 + t;
        #pragma unroll
        for (int i = 0; i < 10; ++i) {
            int e = e0 + i * 256;
            if (e >= NE) continue;
            int d = ei[NE + e];
            if (d >= lo && d < hi) {
                int s = ei[e];
                int pos = atomicAdd(&deg[d], 1);
                if (pos < CAP) bkt[d*CAP + pos] = (unsigned short)s;
            }
        }
    } else if (bid < 16420) {
        int i = (bid - 3920) * 256 + t;          // [0, NN*64)
        int n = i >> 6, c = (i & 63) * 2;
        float x0 = x[n*3+0], x1 = x[n*3+1], x2 = x[n*3+2];
        float v0 = fmaf(x0, w[c],   fmaf(x1, w[HD+c],   fmaf(x2, w[2*HD+c],   b[c])));
        float v1 = fmaf(x0, w[c+1], fmaf(x1, w[HD+c+1], fmaf(x2, w[2*HD+c+1], b[c+1])));
        v0 = fmaxf(v0, 0.f); v1 = fmaxf(v1, 0.f);
        h0[i] = pack2(v0, v1);
    } else if (bid == 16420) {
        if (t < 64)       h0[(long)ZROW*64 + t] = 0u;
        else if (t < 128) h1[(long)ZROW*64 + (t - 64)] = 0u;
    } else {
        int i = (bid - 16421) * 256 + t;         // [0, 2*128*384)
        int ln = i / 384, k = i - ln * 384;      // ln = l*128 + n
        int l = ln >> 7, n = ln & 127;
        const float* wrf = l ? wrf1 : wrf0;
        const float* wrs = l ? wrs1 : wrs0;
        const float* wtf = l ? wtf1 : wtf0;
        const float* wts = l ? wts1 : wts0;
        float v;
        if (k < 128)      v = wrf[k*HD + n];
        else if (k < 256) v = wrs[(k-128)*HD + n];
        else              v = wtf[(k-256)*HD + n] + wts[(k-256)*HD + n];
        Wt[(long)ln*384 + k] = f2bf(0.5f * v);
        if (i < 256) {
            int ll = i >> 7, cc = i & 127;
            const float* bfp = ll ? bf1 : bf0;
            const float* bsp = ll ? bs1 : bs0;
            bcat[i] = 0.5f * (bfp[cc] + bsp[cc]);
        }
    }
}

// agg[n] = mean over bucket[n] of h[src], BOTH relations per wave (node n):
// 32 coalesced row-gathers in flight up front. Invalid slots -> zero row.
__global__ __launch_bounds__(256) void k_spmm(
    const unsigned* __restrict__ h,
    const int* __restrict__ degF, const int* __restrict__ degS,
    const unsigned short* __restrict__ bktF, const unsigned short* __restrict__ bktS,
    unsigned* __restrict__ aggF, unsigned* __restrict__ aggS)
{
    int w = threadIdx.x >> 6, lane = threadIdx.x & 63;
    int n = blockIdx.x * 4 + w;
    int dF = degF[n], dS = degS[n];
    int cF = min(dF, CAP), cS = min(dS, CAP);
    const unsigned short* rowF = bktF + (long)n*CAP;
    const unsigned short* rowS = bktS + (long)n*CAP;
    uint4v uF0 = *(const uint4v*)(rowF);
    uint4v uF1 = *(const uint4v*)(rowF + 8);
    uint4v uS0 = *(const uint4v*)(rowS);
    uint4v uS1 = *(const uint4v*)(rowS + 8);
    unsigned iF[16], iS[16];
    extract8(uF0, 0, cF, iF); extract8(uF1, 8, cF, iF + 8);
    extract8(uS0, 0, cS, iS); extract8(uS1, 8, cS, iS + 8);
    unsigned vF[16], vS[16];
    #pragma unroll
    for (int j = 0; j < 16; ++j) vF[j] = h[iF[j]*64u + lane];
    #pragma unroll
    for (int j = 0; j < 16; ++j) vS[j] = h[iS[j]*64u + lane];
    float aF0 = 0.f, aF1 = 0.f, aS0 = 0.f, aS1 = 0.f;
    #pragma unroll
    for (int j = 0; j < 16; ++j) { aF0 += bflo(vF[j]); aF1 += bfhi(vF[j]); }
    #pragma unroll
    for (int j = 0; j < 16; ++j) { aS0 += bflo(vS[j]); aS1 += bfhi(vS[j]); }
    // tails (P(deg>16) ~ 0.13)
    for (int j = 16; j < cF; j += 8) {
        uint4v u = *(const uint4v*)(rowF + j);
        unsigned ii[8];
        extract8(u, j, cF, ii);
        unsigned vv[8];
        #pragma unroll
        for (int q = 0; q < 8; ++q) vv[q] = h[ii[q]*64u + lane];
        #pragma unroll
        for (int q = 0; q < 8; ++q) { aF0 += bflo(vv[q]); aF1 += bfhi(vv[q]); }
    }
    for (int j = 16; j < cS; j += 8) {
        uint4v u = *(const uint4v*)(rowS + j);
        unsigned ii[8];
        extract8(u, j, cS, ii);
        unsigned vv[8];
        #pragma unroll
        for (int q = 0; q < 8; ++q) vv[q] = h[ii[q]*64u + lane];
        #pragma unroll
        for (int q = 0; q < 8; ++q) { aS0 += bflo(vv[q]); aS1 += bfhi(vv[q]); }
    }
    float invF = 1.f / fmaxf((float)dF, 1.f);
    float invS = 1.f / fmaxf((float)dS, 1.f);
    aggF[n*64 + lane] = pack2(aF0*invF, aF1*invF);
    aggS[n*64 + lane] = pack2(aS0*invS, aS1*invS);
}

// out[M,128] = [A0|A1|A2](M,384, bf16) @ W(384,128, bf16 Wt[n][k]) + bias.
// Wt staged through LDS frag-major (conflict-free ds_read_b128, 4x B-amortize).
// mode 0: relu -> bf16 h1. mode 1: fused classifier epilogue -> out6.
__global__ __launch_bounds__(256) void k_gemm(
    const unsigned short* __restrict__ A0, const unsigned short* __restrict__ A1,
    const unsigned short* __restrict__ A2,
    const unsigned short* __restrict__ Wt, const float* __restrict__ bias,
    unsigned short* __restrict__ outH, int mode,
    const float* __restrict__ ow, const float* __restrict__ ob,
    float* __restrict__ out6)
{
    __shared__ unsigned short Bs[16 * 64 * 8];   // 16 KB
    const int t = threadIdx.x;
    const int wv = t >> 6, lane = t & 63;
    const int m16 = lane & 15, quad = lane >> 4;
    const int row0 = blockIdx.x * 128 + wv * 32;
    f32x4 acc[2][8];
    #pragma unroll
    for (int mt = 0; mt < 2; ++mt)
        #pragma unroll
        for (int nt = 0; nt < 8; ++nt) acc[mt][nt] = (f32x4){0.f,0.f,0.f,0.f};

    for (int ch = 0; ch < 6; ++ch) {
        const int k0 = ch * 64;
        const unsigned short* src; int kofs;
        if (ch < 2)      { src = A0; kofs = k0; }
        else if (ch < 4) { src = A1; kofs = k0 - 128; }
        else             { src = A2; kofs = k0 - 256; }
        __syncthreads();
        #pragma unroll
        for (int i = 0; i < 4; ++i) {
            int flat = i * 256 + t;
            int fb = flat >> 6, ln = flat & 63;
            int nt = fb >> 1, kc2 = fb & 1;
            int mm = ln & 15, qq = ln >> 4;
            short8 v = *(const short8*)(Wt + (long)(nt*16 + mm)*384 + k0 + kc2*32 + qq*8);
            *(short8*)(Bs + flat*8) = v;
        }
        short8 a[2][2];
        #pragma unroll
        for (int mt = 0; mt < 2; ++mt) {
            int r = row0 + mt*16 + m16;
            #pragma unroll
            for (int kc2 = 0; kc2 < 2; ++kc2) {
                if (r < NN) a[mt][kc2] = *(const short8*)(src + (long)r*HD + kofs + kc2*32 + quad*8);
                else        a[mt][kc2] = short8{0,0,0,0,0,0,0,0};
            }
        }
        __syncthreads();
        #pragma unroll
        for (int kc2 = 0; kc2 < 2; ++kc2)
            #pragma unroll
            for (int nt = 0; nt < 8; ++nt) {
                short8 bfr = *(const short8*)(Bs + ((nt*2 + kc2)*64 + lane)*8);
                acc[0][nt] = __builtin_amdgcn_mfma_f32_16x16x32_bf16(a[0][kc2], bfr, acc[0][nt], 0, 0, 0);
                acc[1][nt] = __builtin_amdgcn_mfma_f32_16x16x32_bf16(a[1][kc2], bfr, acc[1][nt], 0, 0, 0);
            }
    }

    float bs[8];
    #pragma unroll
    for (int nt = 0; nt < 8; ++nt) bs[nt] = bias[nt*16 + m16];

    if (mode == 0) {
        #pragma unroll
        for (int mt = 0; mt < 2; ++mt)
            #pragma unroll
            for (int reg = 0; reg < 4; ++reg) {
                int r = row0 + mt*16 + quad*4 + reg;
                if (r >= NN) continue;
                #pragma unroll
                for (int nt = 0; nt < 8; ++nt) {
                    float v = fmaxf(acc[mt][nt][reg] + bs[nt], 0.f);
                    outH[(long)r*HD + nt*16 + m16] = f2bf(v);
                }
            }
    } else {
        float owr[8][6];
        #pragma unroll
        for (int nt = 0; nt < 8; ++nt) {
            int c = nt*16 + m16;
            #pragma unroll
            for (int j = 0; j < 6; ++j) owr[nt][j] = ow[c*6 + j];
        }
        #pragma unroll
        for (int mt = 0; mt < 2; ++mt)
            #pragma unroll
            for (int reg = 0; reg < 4; ++reg) {
                int r = row0 + mt*16 + quad*4 + reg;
                float tj[6] = {0,0,0,0,0,0};
                #pragma unroll
                for (int nt = 0; nt < 8; ++nt) {
                    float hv = acc[mt][nt][reg] + bs[nt];
                    #pragma unroll
                    for (int j = 0; j < 6; ++j) tj[j] = fmaf(hv, owr[nt][j], tj[j]);
                }
                #pragma unroll
                for (int mask = 1; mask < 16; mask <<= 1)
                    #pragma unroll
                    for (int j = 0; j < 6; ++j) tj[j] += __shfl_xor(tj[j], mask, 64);
                if (m16 == 0 && r < NN) {
                    #pragma unroll
                    for (int j = 0; j < 6; ++j) out6[(long)r*6 + j] = tj[j] + ob[j];
                }
            }
    }
}

extern "C" void kernel_launch(void* const* d_in, const int* in_sizes, int n_in,
                              void* d_out, int out_size, void* d_ws, size_t ws_size,
                              hipStream_t stream)
{
    const float* x     = (const float*)d_in[0];
    const int*   ei_f  = (const int*)d_in[1];
    const int*   ei_s  = (const int*)d_in[2];
    const float* emb_w = (const float*)d_in[3];
    const float* emb_b = (const float*)d_in[4];
    const float* wr0f  = (const float*)d_in[5];
    const float* wt0f  = (const float*)d_in[6];
    const float* b0f   = (const float*)d_in[7];
    const float* wr0s  = (const float*)d_in[8];
    const float* wt0s  = (const float*)d_in[9];
    const float* b0s   = (const float*)d_in[10];
    const float* wr1f  = (const float*)d_in[11];
    const float* wt1f  = (const float*)d_in[12];
    const float* b1f   = (const float*)d_in[13];
    const float* wr1s  = (const float*)d_in[14];
    const float* wt1s  = (const float*)d_in[15];
    const float* b1s   = (const float*)d_in[16];
    const float* out_w = (const float*)d_in[17];
    const float* out_b = (const float*)d_in[18];
    float* out = (float*)d_out;

    char* ws = (char*)d_ws;
    size_t off = 0;
    auto alloc = [&](size_t bytes) { char* p = ws + off; off += (bytes + 255) & ~255ULL; return p; };
    unsigned* h0   = (unsigned*)alloc((size_t)(NN+1)*64*4);   // bf16x2 packed, +1 zero row
    unsigned* h1   = (unsigned*)alloc((size_t)(NN+1)*64*4);
    unsigned* aggF = (unsigned*)alloc((size_t)NN*64*4);
    unsigned* aggS = (unsigned*)alloc((size_t)NN*64*4);
    int*   degF = (int*)alloc((size_t)NN*4);
    int*   degS = (int*)alloc((size_t)NN*4);
    unsigned short* bktF = (unsigned short*)alloc((size_t)NN*CAP*2);
    unsigned short* bktS = (unsigned short*)alloc((size_t)NN*CAP*2);
    unsigned short* Wt = (unsigned short*)alloc((size_t)2*128*384*2);
    float* bcat = (float*)alloc((size_t)2*HD*4);

    hipMemsetAsync(degF, 0, NN*4, stream);
    hipMemsetAsync(degS, 0, NN*4, stream);

    k_prep<<<16805, 256, 0, stream>>>(x, emb_w, emb_b, h0, h1,
                                      ei_f, ei_s, degF, degS, bktF, bktS,
                                      wr0f, wt0f, b0f, wr0s, wt0s, b0s,
                                      wr1f, wt1f, b1f, wr1s, wt1s, b1s,
                                      Wt, bcat);
    k_spmm<<<NN/4, 256, 0, stream>>>(h0, degF, degS, bktF, bktS, aggF, aggS);
    k_gemm<<<(NN + 127)/128, 256, 0, stream>>>((const unsigned short*)aggF, (const unsigned short*)aggS,
                                               (const unsigned short*)h0, Wt, bcat,
                                               (unsigned short*)h1, 0, out_w, out_b, out);
    k_spmm<<<NN/4, 256, 0, stream>>>(h1, degF, degS, bktF, bktS, aggF, aggS);
    k_gemm<<<(NN + 127)/128, 256, 0, stream>>>((const unsigned short*)aggF, (const unsigned short*)aggS,
                                               (const unsigned short*)h1, Wt + 128*384, bcat + HD,
                                               (unsigned short*)h1, 1, out_w, out_b, out);
}